// Round 1
// baseline (257.954 us; speedup 1.0000x reference)
//
#include <hip/hip_runtime.h>

// Trilerp of 3 feature levels + mesh-feature concat.
// Output layout: [B, N, 227] = [32 ch lvl1 | 64 ch lvl2 | 128 ch lvl3 | 3 mesh]
// One block per point; lanes = output channels (channel dim is innermost in
// the grids, so each corner gather is a contiguous, coalesced segment).

__global__ __launch_bounds__(256) void trilerp_kernel(
    const float* __restrict__ f1,      // [B,64,64,64,32]
    const float* __restrict__ f2,      // [B,32,32,32,64]
    const float* __restrict__ f3,      // [B,16,16,16,128]
    const float* __restrict__ coords,  // [B,N,3]
    const float* __restrict__ meshf,   // [B,N,3]
    float* __restrict__ out,           // [B,N,227]
    int nPts)                          // N (per batch)
{
    const int pt = blockIdx.x;              // 0 .. B*N-1  (b = pt / N)
    const int t  = threadIdx.x;
    if (t >= 227) return;

    float* o = out + (size_t)pt * 227;

    if (t >= 224) {                          // mesh-feature passthrough
        o[t] = meshf[(size_t)pt * 3 + (t - 224)];
        return;
    }

    const int b = pt / nPts;

    // coords broadcast across lanes (same address -> single cached fetch)
    const float cx = coords[(size_t)pt * 3 + 0];
    const float cy = coords[(size_t)pt * 3 + 1];
    const float cz = coords[(size_t)pt * 3 + 2];

    const float* feat;
    int D, C, c;
    if (t < 32)       { feat = f1; D = 64; C = 32;  c = t;      }
    else if (t < 96)  { feat = f2; D = 32; C = 64;  c = t - 32; }
    else              { feat = f3; D = 16; C = 128; c = t - 96; }

    // scale = 0.5^power * 128 == D for every level; hi computed in double
    // then cast, matching Python's float(min(shape)) - 1.01.
    const float scale = (float)D;
    const float hi    = (float)((double)D - 1.01);

    float ix = fminf(fmaxf(cx * scale, 0.01f), hi);
    float iy = fminf(fmaxf(cy * scale, 0.01f), hi);
    float iz = fminf(fmaxf(cz * scale, 0.01f), hi);

    const float x1f = floorf(ix), x2f = ceilf(ix);
    const float y1f = floorf(iy), y2f = ceilf(iy);
    const float z1f = floorf(iz), z2f = ceilf(iz);
    const int x1 = (int)x1f, x2 = (int)x2f;
    const int y1 = (int)y1f, y2 = (int)y2f;
    const int z1 = (int)z1f, z2 = (int)z2f;

    // Reference weight convention: wx on the x2 (ceil) sample, wx2 on x1.
    const float wx = ix - x1f, wx2 = x2f - ix;
    const float wy = iy - y1f, wy2 = y2f - iy;
    const float wz = iz - z1f, wz2 = z2f - iz;

    const size_t base = (size_t)b * D * D * D * C + c;
    #define OFF(X, Y, Z) (base + (size_t)((((X) * D + (Y)) * D + (Z))) * C)

    const float v111 = feat[OFF(x1, y1, z1)];
    const float v211 = feat[OFF(x2, y1, z1)];
    const float v121 = feat[OFF(x1, y2, z1)];
    const float v221 = feat[OFF(x2, y2, z1)];
    const float v112 = feat[OFF(x1, y1, z2)];
    const float v212 = feat[OFF(x2, y1, z2)];
    const float v122 = feat[OFF(x1, y2, z2)];
    const float v222 = feat[OFF(x2, y2, z2)];
    #undef OFF

    // z = z1 plane
    const float lx1a = v211 * wx + v111 * wx2;
    const float lx2a = v221 * wx + v121 * wx2;
    const float ly1  = lx2a * wy + lx1a * wy2;
    // z = z2 plane
    const float lx1b = v212 * wx + v112 * wx2;
    const float lx2b = v222 * wx + v122 * wx2;
    const float ly2  = lx2b * wy + lx1b * wy2;

    o[t] = ly2 * wz + ly1 * wz2;
}

extern "C" void kernel_launch(void* const* d_in, const int* in_sizes, int n_in,
                              void* d_out, int out_size, void* d_ws, size_t ws_size,
                              hipStream_t stream) {
    const float* f1     = (const float*)d_in[1];  // [B,64,64,64,32]
    const float* f2     = (const float*)d_in[2];  // [B,32,32,32,64]
    const float* f3     = (const float*)d_in[3];  // [B,16,16,16,128]
    const float* coords = (const float*)d_in[5];  // [B,N,3]
    const float* meshf  = (const float*)d_in[6];  // [B,N,3]
    float* out = (float*)d_out;

    const int B = in_sizes[1] / (64 * 64 * 64 * 32);
    const int N = in_sizes[5] / (B * 3);

    trilerp_kernel<<<dim3(B * N), dim3(256), 0, stream>>>(
        f1, f2, f3, coords, meshf, out, N);
}

// Round 2
// 217.149 us; speedup vs baseline: 1.1879x; 1.1879x over previous
//
#include <hip/hip_runtime.h>

// Trilerp of 3 feature levels + mesh-feature concat.
// Output layout: [B, N, 227] = [32 ch lvl1 | 64 ch lvl2 | 128 ch lvl3 | 3 mesh]
// One WAVE (64 lanes) per point; each lane produces 4 channels via float4
// corner gathers (channel dim is innermost -> contiguous, 16B-aligned).
// Lane map: 0-7 lvl1 (32ch), 8-23 lvl2 (64ch), 24-55 lvl3 (128ch),
//           56-58 mesh passthrough, 59-63 idle.
// Block = 256 threads = 4 points. Grid = (ceil(N/4), B) -> no integer div.

__global__ __launch_bounds__(256) void trilerp_kernel(
    const float* __restrict__ f1,      // [B,64,64,64,32]
    const float* __restrict__ f2,      // [B,32,32,32,64]
    const float* __restrict__ f3,      // [B,16,16,16,128]
    const float* __restrict__ coords,  // [B,N,3]
    const float* __restrict__ meshf,   // [B,N,3]
    float* __restrict__ out,           // [B,N,227]
    int N)
{
    const int lane = threadIdx.x & 63;
    const int wv   = threadIdx.x >> 6;
    const int pn   = blockIdx.x * 4 + wv;     // point within batch
    if (pn >= N) return;
    const int b  = blockIdx.y;
    const int pt = b * N + pn;                // global point index

    if (lane >= 56) {                          // mesh-feature passthrough
        if (lane < 59) {
            __builtin_nontemporal_store(meshf[pt * 3 + (lane - 56)],
                                        &out[pt * 227 + 224 + (lane - 56)]);
        }
        return;
    }

    // coords broadcast across the wave (same address -> one cached fetch)
    const float cx = coords[pt * 3 + 0];
    const float cy = coords[pt * 3 + 1];
    const float cz = coords[pt * 3 + 2];

    const float4* fp; int D, C4, c4, oc;
    if (lane < 8)       { fp = (const float4*)f1; D = 64; C4 = 8;  c4 = lane * 4;        oc = c4;      }
    else if (lane < 24) { fp = (const float4*)f2; D = 32; C4 = 16; c4 = (lane - 8) * 4;  oc = 32 + c4; }
    else                { fp = (const float4*)f3; D = 16; C4 = 32; c4 = (lane - 24) * 4; oc = 96 + c4; }

    // scale = 0.5^power * 128 == D; hi matches Python float(min(shape)) - 1.01
    const float scale = (float)D;
    const float hi    = (float)((double)D - 1.01);

    const float ix = fminf(fmaxf(cx * scale, 0.01f), hi);
    const float iy = fminf(fmaxf(cy * scale, 0.01f), hi);
    const float iz = fminf(fmaxf(cz * scale, 0.01f), hi);

    const float x1f = floorf(ix), x2f = ceilf(ix);
    const float y1f = floorf(iy), y2f = ceilf(iy);
    const float z1f = floorf(iz), z2f = ceilf(iz);
    const int x1 = (int)x1f, x2 = (int)x2f;
    const int y1 = (int)y1f, y2 = (int)y2f;
    const int z1 = (int)z1f, z2 = (int)z2f;

    // Reference weight convention: wx multiplies the x2 (ceil) sample.
    const float wx = ix - x1f, wx2 = x2f - ix;
    const float wy = iy - y1f, wy2 = y2f - iy;
    const float wz = iz - z1f, wz2 = z2f - iz;

    // All-int32 float4 indexing (max index ~4.2M < 2^31).
    const int base4 = b * (D * D * D * C4) + (c4 >> 2);
    #define IDX(X, Y, Z) (base4 + (((X) * D + (Y)) * D + (Z)) * C4)

    const float4 v111 = fp[IDX(x1, y1, z1)];
    const float4 v211 = fp[IDX(x2, y1, z1)];
    const float4 v121 = fp[IDX(x1, y2, z1)];
    const float4 v221 = fp[IDX(x2, y2, z1)];
    const float4 v112 = fp[IDX(x1, y1, z2)];
    const float4 v212 = fp[IDX(x2, y1, z2)];
    const float4 v122 = fp[IDX(x1, y2, z2)];
    const float4 v222 = fp[IDX(x2, y2, z2)];
    #undef IDX

    float4 r;
    {   // per-component trilerp, same expression order as the reference
        const float lx1a = v211.x * wx + v111.x * wx2;
        const float lx2a = v221.x * wx + v121.x * wx2;
        const float ly1  = lx2a * wy + lx1a * wy2;
        const float lx1b = v212.x * wx + v112.x * wx2;
        const float lx2b = v222.x * wx + v122.x * wx2;
        const float ly2  = lx2b * wy + lx1b * wy2;
        r.x = ly2 * wz + ly1 * wz2;
    }
    {
        const float lx1a = v211.y * wx + v111.y * wx2;
        const float lx2a = v221.y * wx + v121.y * wx2;
        const float ly1  = lx2a * wy + lx1a * wy2;
        const float lx1b = v212.y * wx + v112.y * wx2;
        const float lx2b = v222.y * wx + v122.y * wx2;
        const float ly2  = lx2b * wy + lx1b * wy2;
        r.y = ly2 * wz + ly1 * wz2;
    }
    {
        const float lx1a = v211.z * wx + v111.z * wx2;
        const float lx2a = v221.z * wx + v121.z * wx2;
        const float ly1  = lx2a * wy + lx1a * wy2;
        const float lx1b = v212.z * wx + v112.z * wx2;
        const float lx2b = v222.z * wx + v122.z * wx2;
        const float ly2  = lx2b * wy + lx1b * wy2;
        r.z = ly2 * wz + ly1 * wz2;
    }
    {
        const float lx1a = v211.w * wx + v111.w * wx2;
        const float lx2a = v221.w * wx + v121.w * wx2;
        const float ly1  = lx2a * wy + lx1a * wy2;
        const float lx1b = v212.w * wx + v112.w * wx2;
        const float lx2b = v222.w * wx + v122.w * wx2;
        const float ly2  = lx2b * wy + lx1b * wy2;
        r.w = ly2 * wz + ly1 * wz2;
    }

    float* o = out + pt * 227 + oc;
    __builtin_nontemporal_store(r.x, o + 0);
    __builtin_nontemporal_store(r.y, o + 1);
    __builtin_nontemporal_store(r.z, o + 2);
    __builtin_nontemporal_store(r.w, o + 3);
}

extern "C" void kernel_launch(void* const* d_in, const int* in_sizes, int n_in,
                              void* d_out, int out_size, void* d_ws, size_t ws_size,
                              hipStream_t stream) {
    const float* f1     = (const float*)d_in[1];  // [B,64,64,64,32]
    const float* f2     = (const float*)d_in[2];  // [B,32,32,32,64]
    const float* f3     = (const float*)d_in[3];  // [B,16,16,16,128]
    const float* coords = (const float*)d_in[5];  // [B,N,3]
    const float* meshf  = (const float*)d_in[6];  // [B,N,3]
    float* out = (float*)d_out;

    const int B = in_sizes[1] / (64 * 64 * 64 * 32);
    const int N = in_sizes[5] / (B * 3);

    trilerp_kernel<<<dim3((N + 3) / 4, B), dim3(256), 0, stream>>>(
        f1, f2, f3, coords, meshf, out, N);
}